// Round 8
// baseline (301.204 us; speedup 1.0000x reference)
//
#include <hip/hip_runtime.h>
#include <math.h>

#define LL 256
#define DD 768
#define HH 384
#define G4 1536
#define NWIN 4
#define NLIN 9
#define NPOS 1024        // B*L
#define PROJ_N 12288     // 8 chains * 1536
#define HSTRIDE 520      // padded LDS ks-stride (shorts): bank-spreads H writes

typedef __attribute__((ext_vector_type(8))) short short8;
typedef __attribute__((ext_vector_type(4))) short short4v;
typedef __attribute__((ext_vector_type(16))) float f32x16;

static __device__ __forceinline__ float bf2f(unsigned short u) {
    union { unsigned int i; float f; } v; v.i = ((unsigned int)u) << 16; return v.f;
}
static __device__ __forceinline__ unsigned short f2bf(float f) {
    unsigned int u = __float_as_uint(f);
    u += 0x7fff + ((u >> 16) & 1);   // round-to-nearest-even
    return (unsigned short)(u >> 16);
}
static __device__ __forceinline__ float fsig(float x) {
    return __builtin_amdgcn_rcpf(1.f + __expf(-x));
}
static __device__ __forceinline__ float ftanh(float x) {
    return 1.f - 2.f * __builtin_amdgcn_rcpf(1.f + __expf(2.f * x));
}

// ---------------------------------------------------------------- prep: scatter(+zero), weight casts, out-init
__global__ __launch_bounds__(256) void prep_kernel(
        const float* __restrict__ seq, const int* __restrict__ valid,
        unsigned short* __restrict__ xfrag,
        const float* __restrict__ wihF, const float* __restrict__ wihB,
        unsigned short* __restrict__ wfih,
        const float* __restrict__ whhF, const float* __restrict__ whhB,
        unsigned short* __restrict__ wfhh,
        const float* __restrict__ lin_b, float* __restrict__ out) {
    const int tid = threadIdx.x;
    if (blockIdx.x < 128) {
        // ---------------- scatter + tail-zero (ballot-scan)
        const int b = blockIdx.x >> 5;
        const int chunk = blockIdx.x & 31;
        __shared__ int dest[LL];
        __shared__ int wsum[4];
        __shared__ int nvalid;
        const int v = valid[b * LL + tid];
        const unsigned long long m = __ballot(v != 0);
        const int lane = tid & 63, wvi = tid >> 6;
        const int pre = __popcll(m & (((unsigned long long)1 << lane) - 1));
        if (lane == 63) wsum[wvi] = pre + (v ? 1 : 0);
        __syncthreads();
        int base = 0;
#pragma unroll
        for (int k = 0; k < 4; ++k) if (k < wvi) base += wsum[k];
        dest[tid] = v ? (base + pre) : -1;
        if (tid == 0) nvalid = wsum[0] + wsum[1] + wsum[2] + wsum[3];
        __syncthreads();
        const int nv = nvalid;
        for (int l = chunk * 8; l < chunk * 8 + 8; ++l) {
            const int d = dest[l];
            if (d >= 0) {
                const float* src = seq + (size_t)(b * LL + l) * DD;
                const int pos = b * LL + d;
                const int pt = pos >> 5, pl = pos & 31;
                for (int j = tid; j < DD / 8; j += 256) {
                    const float4 v0 = ((const float4*)src)[2 * j];
                    const float4 v1 = ((const float4*)src)[2 * j + 1];
                    short8 pv;
                    pv[0] = (short)f2bf(v0.x); pv[1] = (short)f2bf(v0.y);
                    pv[2] = (short)f2bf(v0.z); pv[3] = (short)f2bf(v0.w);
                    pv[4] = (short)f2bf(v1.x); pv[5] = (short)f2bf(v1.y);
                    pv[6] = (short)f2bf(v1.z); pv[7] = (short)f2bf(v1.w);
                    *(short8*)(xfrag + ((size_t)(pt * 48 + (j >> 1)) * 512 + (pl + 32 * (j & 1)) * 8)) = pv;
                }
            }
            if (l >= nv) {   // dest slot l never written: zero its frag row
                const int pos = b * LL + l;
                const int pt = pos >> 5, pl = pos & 31;
                const short8 zv = {};
                for (int j = tid; j < DD / 8; j += 256)
                    *(short8*)(xfrag + ((size_t)(pt * 48 + (j >> 1)) * 512 + (pl + 32 * (j & 1)) * 8)) = zv;
            }
        }
    } else if (blockIdx.x < 896) {
        // ---------------- cast weights -> B-fragment layout
        __shared__ unsigned short lds[32 * 768];
        const int cb = blockIdx.x - 128;
        const int isIH = cb < 384;
        const int vblk = isIH ? cb : (cb - 384);
        const int K = isIH ? DD : HH;
        const float* srcF = isIH ? wihF : whhF;
        const float* srcB = isIH ? wihB : whhB;
        unsigned short* dst = isIH ? wfih : wfhh;
        const int vrow0 = vblk * 32;
        const int chain = vrow0 / G4;
        const int dir = chain >> 2, wi = chain & 3;
        const float* src = (dir ? srcB : srcF) + (size_t)(wi * G4 + (vrow0 % G4)) * K;
        const int total = 32 * K;
        for (int i = tid * 4; i < total; i += 1024) {
            const float4 v = *(const float4*)(src + i);
            lds[i + 0] = f2bf(v.x); lds[i + 1] = f2bf(v.y);
            lds[i + 2] = f2bf(v.z); lds[i + 3] = f2bf(v.w);
        }
        __syncthreads();
        const int nks = K >> 4;
        for (int slot = tid; slot < nks * 64; slot += 256) {
            const int ks = slot >> 6;
            const int lane = slot & 63;
            const int row = lane & 31;
            const int kb = ks * 16 + (lane >> 5) * 8;
            const short8 v = *(const short8*)&lds[row * K + kb];
            *(short8*)(dst + ((size_t)vblk * nks + ks) * 512 + lane * 8) = v;
        }
    } else {
        // ---------------- seed out with lin_b (attn_out2 atomicAdds partials)
        for (int i = tid; i < NPOS * NLIN; i += 256)
            out[i] = lin_b[i % NLIN];
    }
}

// ---------------------------------------------------------------- proj GEMM (MFMA)
__global__ __launch_bounds__(256) void proj_mfma(
        const unsigned short* __restrict__ xf,
        const unsigned short* __restrict__ wf,
        const float* __restrict__ bihf, const float* __restrict__ bhhf,
        const float* __restrict__ bihb, const float* __restrict__ bhhb,
        unsigned short* __restrict__ proj) {
    __shared__ __align__(16) unsigned short st[4 * 4096];   // 32 KB
    const int wv = threadIdx.x >> 6;        // gate
    const int lane = threadIdx.x & 63;
    const int colid = lane & 31, hq = lane >> 5;
    const int chain = blockIdx.x & 7;       // XCD id
    const int r8 = blockIdx.x >> 3;         // 0..95
    const int us = r8 % 12;
    const int mtg = r8 / 12;                // 0..7
    const int dir = chain >> 2, wi = chain & 3;

    const unsigned short* bP = wf + (size_t)((chain * 48 + wv * 12 + us) * 48) * 512 + lane * 8;
    const unsigned short* aP = xf + (size_t)(mtg * 4 * 48) * 512 + lane * 8;

    f32x16 acc[4] = {};
#pragma unroll 4
    for (int ks = 0; ks < 48; ++ks) {
        const short8 bv = *(const short8*)(bP + ks * 512);
        const short8 a0 = *(const short8*)(aP + (0 * 48 + ks) * 512);
        const short8 a1 = *(const short8*)(aP + (1 * 48 + ks) * 512);
        const short8 a2 = *(const short8*)(aP + (2 * 48 + ks) * 512);
        const short8 a3 = *(const short8*)(aP + (3 * 48 + ks) * 512);
        acc[0] = __builtin_amdgcn_mfma_f32_32x32x16_bf16(a0, bv, acc[0], 0, 0, 0);
        acc[1] = __builtin_amdgcn_mfma_f32_32x32x16_bf16(a1, bv, acc[1], 0, 0, 0);
        acc[2] = __builtin_amdgcn_mfma_f32_32x32x16_bf16(a2, bv, acc[2], 0, 0, 0);
        acc[3] = __builtin_amdgcn_mfma_f32_32x32x16_bf16(a3, bv, acc[3], 0, 0, 0);
    }
    const int br = wv * HH + us * 32 + colid;
    const float bv = (dir ? bihb : bihf)[wi * G4 + br] + (dir ? bhhb : bhhf)[wi * G4 + br];
#pragma unroll
    for (int i = 0; i < 4; ++i) {
#pragma unroll
        for (int r = 0; r < 16; ++r) {
            const int row = (r & 3) + 8 * (r >> 2) + 4 * hq;
            st[i * 4096 + (row * 32 + colid) * 4 + wv] = f2bf(acc[i][r] + bv);
        }
    }
    __syncthreads();
#pragma unroll
    for (int j = 0; j < 8; ++j) {
        const int idx = j * 256 + threadIdx.x;
        const int i = idx >> 9, rem = idx & 511;
        const int pl = rem >> 4, q = rem & 15;
        const int pos = (mtg * 4 + i) * 32 + pl;
        *(int4*)(proj + (size_t)pos * PROJ_N + chain * G4 + us * 128 + q * 8) =
            ((const int4*)st)[idx];
    }
}

// ---------------------------------------------------------------- fused LSTM recurrence (two-pass gates, si in LDS)
// FALSIFIED, do not retry: XCD remap (r1), reg W-pipeline / M=64 (r2/r4/r5,
// 84-VGPR compiler cap), K-stagger (r6), launch_bounds change (r5).
// THIS ROUND'S THEORY: r0 structure demands 64 acc + 32 pj = 96 regs >
// 84 cap -> W loads can't pipeline, each step serializes ~96 L2/L3-latency
// loads in tiny batches (step 16 us vs ~1 us MFMA floor). Two-pass fix:
// pass A (i,f): 2 accs + 16-reg pj; si -> LDS f32 (per-thread slot,
// conflict-free [r*768+tid], no barrier); c *= sig(gf).
// pass B (g,o): 2 accs + 16-reg pj; c = fmaf(si, tanh(gg), c); h out.
// Live set ~68-80 <= 84 -> ~2x load pipeline depth. W still read once per
// step. Numerics = r4's two-pass (passed). Spill sentinel: WRITE ~8.4 MB.
__global__ __launch_bounds__(768, 3) void lstm_fused(
        const unsigned short* __restrict__ Wf,
        const unsigned short* __restrict__ proj,
        unsigned short* __restrict__ hfin) {
    const int p = blockIdx.x & 3, sub = (blockIdx.x >> 2) & 1;
    const int slot = blockIdx.x >> 3;
    const int chainA[4] = {3, 7, 2, 6};   // w=9,9,7,7
    const int chainB[4] = {0, 4, 1, 5};   // w=3,3,5,5
    const int chain = (slot < 16) ? chainA[p] : chainB[p];
    const int pt = sub * 16 + (slot & 15);
    const int dir = chain >> 2, wi = chain & 3;
    const int w = 3 + 2 * wi, half = wi + 1;
    const int tid = threadIdx.x;
    const int lane = tid & 63, wv = tid >> 6;   // wv 0..11 = unit slice
    const int colid = lane & 31, hq = lane >> 5;
    const int uu = wv * 32 + colid;
    const int m0 = pt * 32, b = m0 >> 8, l0 = m0 & 255;

    __shared__ __align__(16) unsigned short Hbuf[2][24 * HSTRIDE];   // ~50 KB
    __shared__ float si_lds[16 * 768];                               // 48 KB
    float c[16];
#pragma unroll
    for (int r = 0; r < 16; ++r) c[r] = 0.f;

    const unsigned short* projb = proj + (size_t)(b * LL) * PROJ_N + chain * G4 + uu * 4;
    const unsigned short* Wb = Wf + (size_t)((chain * 48 + wv) * 24) * 512 + lane * 8;
    const int ksp = uu >> 4, khp = (uu >> 3) & 1, jp = uu & 7;
    const int hslot = ksp * HSTRIDE + khp * 256 + jp;   // + row*8

    for (int s = 0; s < w; ++s) {
        const int t = dir ? (w - 1 - s) : s;
        const int tmh = t - half;
        unsigned short* cur = Hbuf[s & 1];
        const unsigned short* prev = Hbuf[(s & 1) ^ 1];
        const unsigned short* Alds = prev + lane * 8;

        // ---------- pass A: gates i (g=0), f (g=1)
        unsigned int pja[16];
#pragma unroll
        for (int r = 0; r < 16; ++r) {
            const int row = (r & 3) + 8 * (r >> 2) + 4 * hq;
            int src = l0 + row + tmh;
            src = src < 0 ? 0 : (src > LL - 1 ? LL - 1 : src);
            pja[r] = __builtin_nontemporal_load((const unsigned int*)(projb + src * PROJ_N));
        }
        f32x16 acc0 = {}, acc1 = {};
        if (s > 0) {   // s==0: H is zero, gates = proj only
#pragma unroll 4
            for (int ks = 0; ks < 24; ++ks) {
                const short8 av  = *(const short8*)(Alds + ks * HSTRIDE);
                const short8 bv0 = *(const short8*)(Wb + (size_t)(0 * 288 + ks) * 512);
                const short8 bv1 = *(const short8*)(Wb + (size_t)(1 * 288 + ks) * 512);
                acc0 = __builtin_amdgcn_mfma_f32_32x32x16_bf16(av, bv0, acc0, 0, 0, 0);
                acc1 = __builtin_amdgcn_mfma_f32_32x32x16_bf16(av, bv1, acc1, 0, 0, 0);
            }
        }
#pragma unroll
        for (int r = 0; r < 16; ++r) {
            const int row = (r & 3) + 8 * (r >> 2) + 4 * hq;
            const int src = l0 + row + tmh;
            if (src >= 0 && src < LL) {
                si_lds[r * 768 + tid] = fsig(acc0[r] + bf2f((unsigned short)(pja[r] & 0xffff)));
                c[r] = c[r] * fsig(acc1[r] + bf2f((unsigned short)(pja[r] >> 16)));
            }
        }

        // ---------- pass B: gates g (2), o (3)
        unsigned int pjb[16];
#pragma unroll
        for (int r = 0; r < 16; ++r) {
            const int row = (r & 3) + 8 * (r >> 2) + 4 * hq;
            int src = l0 + row + tmh;
            src = src < 0 ? 0 : (src > LL - 1 ? LL - 1 : src);
            pjb[r] = __builtin_nontemporal_load((const unsigned int*)(projb + src * PROJ_N + 2));
        }
        f32x16 acc2 = {}, acc3 = {};
        if (s > 0) {
#pragma unroll 4
            for (int ks = 0; ks < 24; ++ks) {
                const short8 av  = *(const short8*)(Alds + ks * HSTRIDE);
                const short8 bv2 = *(const short8*)(Wb + (size_t)(2 * 288 + ks) * 512);
                const short8 bv3 = *(const short8*)(Wb + (size_t)(3 * 288 + ks) * 512);
                acc2 = __builtin_amdgcn_mfma_f32_32x32x16_bf16(av, bv2, acc2, 0, 0, 0);
                acc3 = __builtin_amdgcn_mfma_f32_32x32x16_bf16(av, bv3, acc3, 0, 0, 0);
            }
        }
#pragma unroll
        for (int r = 0; r < 16; ++r) {
            const int row = (r & 3) + 8 * (r >> 2) + 4 * hq;
            const int src = l0 + row + tmh;
            unsigned short hv;
            if (src >= 0 && src < LL) {
                const float tg = ftanh(acc2[r] + bf2f((unsigned short)(pjb[r] & 0xffff)));
                const float so = fsig(acc3[r] + bf2f((unsigned short)(pjb[r] >> 16)));
                c[r] = fmaf(si_lds[r * 768 + tid], tg, c[r]);
                hv = f2bf(so * ftanh(c[r]));
            } else {
                hv = (s == 0) ? (unsigned short)0 : prev[hslot + row * 8];
            }
            cur[hslot + row * 8] = hv;
        }
        __syncthreads();   // writes visible before next step's reads
    }

    // ---- final H -> global (unpadded hfrag layout)
    const unsigned short* fin = Hbuf[(w - 1) & 1];
    unsigned short* ho = hfin + (size_t)chain * (NPOS * HH) + (size_t)pt * 12288;
#pragma unroll
    for (int i = tid; i < 1536; i += 768) {
        const int ks = i >> 6, off = i & 63;
        *(int4*)(ho + ks * 512 + off * 8) = *(const int4*)(fin + ks * HSTRIDE + off * 8);
    }
}

// ---------------------------------------------------------------- attention, stage 1: partial scores
__global__ __launch_bounds__(192) void attn_scores_kernel(
        const unsigned short* __restrict__ xfrag,
        const unsigned short* __restrict__ hfin,
        float* __restrict__ scores) {
    const int pt = blockIdx.x >> 3, seg = blockIdx.x & 7;
    const int dir = seg >> 2, q = seg & 3;
    const int tid = threadIdx.x;
    const int lane = tid & 63, wv3 = tid >> 6;
    const int pos = lane & 31;
    __shared__ float scp[3][4][32];

    const unsigned short* xb = xfrag + ((size_t)(pt * 48 + 24 * dir)) * 512 + lane * 8;
    const unsigned short* hb0 = hfin + (size_t)(dir * 4) * (NPOS * HH) + (size_t)pt * 12288 + lane * 8;

    float sc4[4] = {0.f, 0.f, 0.f, 0.f};
#pragma unroll
    for (int k = 0; k < 2; ++k) {
        const int ks = q * 6 + wv3 * 2 + k;
        const short8 xv = *(const short8*)(xb + ks * 512);
        float xf[8];
#pragma unroll
        for (int j = 0; j < 8; ++j) xf[j] = bf2f((unsigned short)xv[j]);
#pragma unroll
        for (int wi = 0; wi < 4; ++wi) {
            const short8 hv = *(const short8*)(hb0 + (size_t)wi * (NPOS * HH) + ks * 512);
#pragma unroll
            for (int j = 0; j < 8; ++j)
                sc4[wi] = fmaf(xf[j], bf2f((unsigned short)hv[j]), sc4[wi]);
        }
    }
#pragma unroll
    for (int wi = 0; wi < 4; ++wi) sc4[wi] += __shfl_down(sc4[wi], 32);
    if (lane < 32) {
#pragma unroll
        for (int wi = 0; wi < 4; ++wi) scp[wv3][wi][pos] = sc4[wi];
    }
    __syncthreads();
    if (tid < 32) {
#pragma unroll
        for (int wi = 0; wi < 4; ++wi) {
            const float v = scp[0][wi][tid] + scp[1][wi][tid] + scp[2][wi][tid];
            scores[(((size_t)pt * 8 + seg) * 4 + wi) * 32 + tid] = v;
        }
    }
}

// ---------------------------------------------------------------- attention, stage 2: softmax + output
__global__ __launch_bounds__(192) void attn_out2_kernel(
        const unsigned short* __restrict__ xfrag,
        const unsigned short* __restrict__ hfin,
        const float* __restrict__ scores,
        const float* __restrict__ lin_w,
        float* __restrict__ out) {
    const int pt = blockIdx.x >> 3, seg = blockIdx.x & 7;
    const int dir = seg >> 2, q = seg & 3;
    const int tid = threadIdx.x;
    const int lane = tid & 63, wv3 = tid >> 6;
    const int pos = lane & 31, kh = lane >> 5;
    const float inv_sqrt_d = 0.03608439182435161f;
    __shared__ float redp[3][32][10];

    float s[4];
#pragma unroll
    for (int wi = 0; wi < 4; ++wi) {
        float v = 0.f;
#pragma unroll
        for (int s2 = 0; s2 < 8; ++s2)
            v += scores[(((size_t)pt * 8 + s2) * 4 + wi) * 32 + pos];
        s[wi] = v * inv_sqrt_d;
    }
    float mx = fmaxf(fmaxf(s[0], s[1]), fmaxf(s[2], s[3]));
    float denom = 0.f;
    float aw[4];
#pragma unroll
    for (int wi = 0; wi < 4; ++wi) { aw[wi] = __expf(s[wi] - mx); denom += aw[wi]; }
    const float rd = __builtin_amdgcn_rcpf(denom);
#pragma unroll
    for (int wi = 0; wi < 4; ++wi) aw[wi] *= rd;

    const unsigned short* xb = xfrag + ((size_t)(pt * 48 + 24 * dir)) * 512 + lane * 8;
    const unsigned short* hb0 = hfin + (size_t)(dir * 4) * (NPOS * HH) + (size_t)pt * 12288 + lane * 8;

    float rp[9];
#pragma unroll
    for (int r = 0; r < 9; ++r) rp[r] = 0.f;
#pragma unroll
    for (int k = 0; k < 2; ++k) {
        const int ks = q * 6 + wv3 * 2 + k;
        const short8 xv = *(const short8*)(xb + ks * 512);
        float ov[8];
#pragma unroll
        for (int j = 0; j < 8; ++j) ov[j] = bf2f((unsigned short)xv[j]);
#pragma unroll
        for (int wi = 0; wi < 4; ++wi) {
            const short8 hv = *(const short8*)(hb0 + (size_t)wi * (NPOS * HH) + ks * 512);
#pragma unroll
            for (int j = 0; j < 8; ++j)
                ov[j] = fmaf(aw[wi], bf2f((unsigned short)hv[j]), ov[j]);
        }
        const int dbase = dir * 384 + ks * 16 + kh * 8;
#pragma unroll
        for (int r = 0; r < 9; ++r) {
            const float4 lw0 = *(const float4*)(lin_w + r * DD + dbase);
            const float4 lw1 = *(const float4*)(lin_w + r * DD + dbase + 4);
            rp[r] += ov[0] * lw0.x + ov[1] * lw0.y + ov[2] * lw0.z + ov[3] * lw0.w
                   + ov[4] * lw1.x + ov[5] * lw1.y + ov[6] * lw1.z + ov[7] * lw1.w;
        }
    }
#pragma unroll
    for (int r = 0; r < 9; ++r) rp[r] += __shfl_down(rp[r], 32);
    if (lane < 32) {
#pragma unroll
        for (int r = 0; r < 9; ++r) redp[wv3][pos][r] = rp[r];
    }
    __syncthreads();
    if (tid < 96) {
#pragma unroll
        for (int e = 0; e < 3; ++e) {
            const int flat = tid * 3 + e;
            const int p2 = flat / 9, r = flat % 9;
            const float sum = redp[0][p2][r] + redp[1][p2][r] + redp[2][p2][r];
            atomicAdd(&out[(size_t)(pt * 32 + p2) * NLIN + r], sum);
        }
    }
}

// ---------------------------------------------------------------- launch
extern "C" void kernel_launch(void* const* d_in, const int* in_sizes, int n_in,
                              void* d_out, int out_size, void* d_ws, size_t ws_size,
                              hipStream_t stream) {
    (void)in_sizes; (void)n_in; (void)out_size; (void)ws_size;
    const float* seq   = (const float*)d_in[0];
    const int*   valid = (const int*)d_in[1];
    const float* wih_f = (const float*)d_in[2];
    const float* whh_f = (const float*)d_in[3];
    const float* bih_f = (const float*)d_in[4];
    const float* bhh_f = (const float*)d_in[5];
    const float* wih_b = (const float*)d_in[6];
    const float* whh_b = (const float*)d_in[7];
    const float* bih_b = (const float*)d_in[8];
    const float* bhh_b = (const float*)d_in[9];
    const float* lin_w = (const float*)d_in[10];
    const float* lin_b = (const float*)d_in[11];
    float* out = (float*)d_out;

    // workspace layout (~61.5 MB)
    unsigned short* xfrag = (unsigned short*)d_ws;                 // 786432 bf16
    unsigned short* proj  = xfrag + (size_t)NPOS * DD;             // 12582912 bf16
    unsigned short* wfhh  = proj + (size_t)NPOS * PROJ_N;          // 4718592 bf16
    unsigned short* wfih  = wfhh + (size_t)4718592;                // 9437184 bf16
    unsigned short* hfin  = wfih + (size_t)9437184;                // 3145728 bf16
    float* scores = (float*)(hfin + (size_t)3145728);              // 128 KB

    prep_kernel<<<897, 256, 0, stream>>>(seq, valid, xfrag,
                                         wih_f, wih_b, wfih,
                                         whh_f, whh_b, wfhh,
                                         lin_b, out);
    proj_mfma<<<768, 256, 0, stream>>>(xfrag, wfih, bih_f, bhh_f, bih_b, bhh_b, proj);
    lstm_fused<<<256, 768, 0, stream>>>(wfhh, proj, hfin);
    attn_scores_kernel<<<256, 192, 0, stream>>>(xfrag, hfin, scores);
    attn_out2_kernel<<<256, 192, 0, stream>>>(xfrag, hfin, scores, lin_w, out);
}

// Round 9
// 277.297 us; speedup vs baseline: 1.0862x; 1.0862x over previous
//
#include <hip/hip_runtime.h>
#include <math.h>

#define LL 256
#define DD 768
#define HH 384
#define G4 1536
#define NWIN 4
#define NLIN 9
#define NPOS 1024        // B*L
#define PROJ_N 12288     // 8 chains * 1536
#define HSTRIDE 520      // padded LDS ks-stride (shorts): bank-spreads H writes

typedef __attribute__((ext_vector_type(8))) short short8;
typedef __attribute__((ext_vector_type(4))) short short4v;
typedef __attribute__((ext_vector_type(16))) float f32x16;

static __device__ __forceinline__ float bf2f(unsigned short u) {
    union { unsigned int i; float f; } v; v.i = ((unsigned int)u) << 16; return v.f;
}
static __device__ __forceinline__ unsigned short f2bf(float f) {
    unsigned int u = __float_as_uint(f);
    u += 0x7fff + ((u >> 16) & 1);   // round-to-nearest-even
    return (unsigned short)(u >> 16);
}
static __device__ __forceinline__ float fsig(float x) {
    return __builtin_amdgcn_rcpf(1.f + __expf(-x));
}
static __device__ __forceinline__ float ftanh(float x) {
    return 1.f - 2.f * __builtin_amdgcn_rcpf(1.f + __expf(2.f * x));
}

// ---------------------------------------------------------------- prep: scatter(+zero), weight casts, out-init
__global__ __launch_bounds__(256) void prep_kernel(
        const float* __restrict__ seq, const int* __restrict__ valid,
        unsigned short* __restrict__ xfrag,
        const float* __restrict__ wihF, const float* __restrict__ wihB,
        unsigned short* __restrict__ wfih,
        const float* __restrict__ whhF, const float* __restrict__ whhB,
        unsigned short* __restrict__ wfhh,
        const float* __restrict__ lin_b, float* __restrict__ out) {
    const int tid = threadIdx.x;
    if (blockIdx.x < 128) {
        // ---------------- scatter + tail-zero (ballot-scan)
        const int b = blockIdx.x >> 5;
        const int chunk = blockIdx.x & 31;
        __shared__ int dest[LL];
        __shared__ int wsum[4];
        __shared__ int nvalid;
        const int v = valid[b * LL + tid];
        const unsigned long long m = __ballot(v != 0);
        const int lane = tid & 63, wvi = tid >> 6;
        const int pre = __popcll(m & (((unsigned long long)1 << lane) - 1));
        if (lane == 63) wsum[wvi] = pre + (v ? 1 : 0);
        __syncthreads();
        int base = 0;
#pragma unroll
        for (int k = 0; k < 4; ++k) if (k < wvi) base += wsum[k];
        dest[tid] = v ? (base + pre) : -1;
        if (tid == 0) nvalid = wsum[0] + wsum[1] + wsum[2] + wsum[3];
        __syncthreads();
        const int nv = nvalid;
        for (int l = chunk * 8; l < chunk * 8 + 8; ++l) {
            const int d = dest[l];
            if (d >= 0) {
                const float* src = seq + (size_t)(b * LL + l) * DD;
                const int pos = b * LL + d;
                const int pt = pos >> 5, pl = pos & 31;
                for (int j = tid; j < DD / 8; j += 256) {
                    const float4 v0 = ((const float4*)src)[2 * j];
                    const float4 v1 = ((const float4*)src)[2 * j + 1];
                    short8 pv;
                    pv[0] = (short)f2bf(v0.x); pv[1] = (short)f2bf(v0.y);
                    pv[2] = (short)f2bf(v0.z); pv[3] = (short)f2bf(v0.w);
                    pv[4] = (short)f2bf(v1.x); pv[5] = (short)f2bf(v1.y);
                    pv[6] = (short)f2bf(v1.z); pv[7] = (short)f2bf(v1.w);
                    *(short8*)(xfrag + ((size_t)(pt * 48 + (j >> 1)) * 512 + (pl + 32 * (j & 1)) * 8)) = pv;
                }
            }
            if (l >= nv) {   // dest slot l never written: zero its frag row
                const int pos = b * LL + l;
                const int pt = pos >> 5, pl = pos & 31;
                const short8 zv = {};
                for (int j = tid; j < DD / 8; j += 256)
                    *(short8*)(xfrag + ((size_t)(pt * 48 + (j >> 1)) * 512 + (pl + 32 * (j & 1)) * 8)) = zv;
            }
        }
    } else if (blockIdx.x < 896) {
        // ---------------- cast weights -> B-fragment layout
        __shared__ unsigned short lds[32 * 768];
        const int cb = blockIdx.x - 128;
        const int isIH = cb < 384;
        const int vblk = isIH ? cb : (cb - 384);
        const int K = isIH ? DD : HH;
        const float* srcF = isIH ? wihF : whhF;
        const float* srcB = isIH ? wihB : whhB;
        unsigned short* dst = isIH ? wfih : wfhh;
        const int vrow0 = vblk * 32;
        const int chain = vrow0 / G4;
        const int dir = chain >> 2, wi = chain & 3;
        const float* src = (dir ? srcB : srcF) + (size_t)(wi * G4 + (vrow0 % G4)) * K;
        const int total = 32 * K;
        for (int i = tid * 4; i < total; i += 1024) {
            const float4 v = *(const float4*)(src + i);
            lds[i + 0] = f2bf(v.x); lds[i + 1] = f2bf(v.y);
            lds[i + 2] = f2bf(v.z); lds[i + 3] = f2bf(v.w);
        }
        __syncthreads();
        const int nks = K >> 4;
        for (int slot = tid; slot < nks * 64; slot += 256) {
            const int ks = slot >> 6;
            const int lane = slot & 63;
            const int row = lane & 31;
            const int kb = ks * 16 + (lane >> 5) * 8;
            const short8 v = *(const short8*)&lds[row * K + kb];
            *(short8*)(dst + ((size_t)vblk * nks + ks) * 512 + lane * 8) = v;
        }
    } else {
        // ---------------- seed out with lin_b (attn_out2 atomicAdds partials)
        for (int i = tid; i < NPOS * NLIN; i += 256)
            out[i] = lin_b[i % NLIN];
    }
}

// ---------------------------------------------------------------- proj GEMM (MFMA)
__global__ __launch_bounds__(256) void proj_mfma(
        const unsigned short* __restrict__ xf,
        const unsigned short* __restrict__ wf,
        const float* __restrict__ bihf, const float* __restrict__ bhhf,
        const float* __restrict__ bihb, const float* __restrict__ bhhb,
        unsigned short* __restrict__ proj) {
    __shared__ __align__(16) unsigned short st[4 * 4096];   // 32 KB
    const int wv = threadIdx.x >> 6;        // gate
    const int lane = threadIdx.x & 63;
    const int colid = lane & 31, hq = lane >> 5;
    const int chain = blockIdx.x & 7;       // XCD id
    const int r8 = blockIdx.x >> 3;         // 0..95
    const int us = r8 % 12;
    const int mtg = r8 / 12;                // 0..7
    const int dir = chain >> 2, wi = chain & 3;

    const unsigned short* bP = wf + (size_t)((chain * 48 + wv * 12 + us) * 48) * 512 + lane * 8;
    const unsigned short* aP = xf + (size_t)(mtg * 4 * 48) * 512 + lane * 8;

    f32x16 acc[4] = {};
#pragma unroll 4
    for (int ks = 0; ks < 48; ++ks) {
        const short8 bv = *(const short8*)(bP + ks * 512);
        const short8 a0 = *(const short8*)(aP + (0 * 48 + ks) * 512);
        const short8 a1 = *(const short8*)(aP + (1 * 48 + ks) * 512);
        const short8 a2 = *(const short8*)(aP + (2 * 48 + ks) * 512);
        const short8 a3 = *(const short8*)(aP + (3 * 48 + ks) * 512);
        acc[0] = __builtin_amdgcn_mfma_f32_32x32x16_bf16(a0, bv, acc[0], 0, 0, 0);
        acc[1] = __builtin_amdgcn_mfma_f32_32x32x16_bf16(a1, bv, acc[1], 0, 0, 0);
        acc[2] = __builtin_amdgcn_mfma_f32_32x32x16_bf16(a2, bv, acc[2], 0, 0, 0);
        acc[3] = __builtin_amdgcn_mfma_f32_32x32x16_bf16(a3, bv, acc[3], 0, 0, 0);
    }
    const int br = wv * HH + us * 32 + colid;
    const float bv = (dir ? bihb : bihf)[wi * G4 + br] + (dir ? bhhb : bhhf)[wi * G4 + br];
#pragma unroll
    for (int i = 0; i < 4; ++i) {
#pragma unroll
        for (int r = 0; r < 16; ++r) {
            const int row = (r & 3) + 8 * (r >> 2) + 4 * hq;
            st[i * 4096 + (row * 32 + colid) * 4 + wv] = f2bf(acc[i][r] + bv);
        }
    }
    __syncthreads();
#pragma unroll
    for (int j = 0; j < 8; ++j) {
        const int idx = j * 256 + threadIdx.x;
        const int i = idx >> 9, rem = idx & 511;
        const int pl = rem >> 4, q = rem & 15;
        const int pos = (mtg * 4 + i) * 32 + pl;
        *(int4*)(proj + (size_t)pos * PROJ_N + chain * G4 + us * 128 + q * 8) =
            ((const int4*)st)[idx];
    }
}

// ---------------------------------------------------------------- fused LSTM recurrence (r0 structure, proj loads CACHED)
// FALSIFIED ledger, do not retry: XCD remap (r1), reg W-pipeline (r2),
// M=64 (r4/r5 -- compiler pins 84 VGPR), launch_bounds (r5), K-stagger
// (r6), two-pass gates / si-in-LDS (r8: W stream split -> L2 eviction,
// FETCH 57->90 MB, 163 us).
// THIS ROUND: drop NONTEMPORAL on proj. NT forces ~98 KB/block/step of
// proj reads to HBM/L3 latency (~600-900 cyc) every step even though the
// clamped window re-reads the same rows up to w times. 16 NT loads/thread
// /step under the 84-reg cap = long latency chain, invariant to co-active
// blocks (matches r6). NT's premise (protect W in L2) was falsified in
// r1/r6 (not W-BW-bound). Plain loads -> proj L2-hits (~200 cyc).
// Sentinel: lstm FETCH should DROP toward 30-40 MB; if it RISES (W
// thrash), theory dead.
__global__ __launch_bounds__(768, 3) void lstm_fused(
        const unsigned short* __restrict__ Wf,
        const unsigned short* __restrict__ proj,
        unsigned short* __restrict__ hfin) {
    const int p = blockIdx.x & 3, sub = (blockIdx.x >> 2) & 1;
    const int slot = blockIdx.x >> 3;
    const int chainA[4] = {3, 7, 2, 6};   // w=9,9,7,7
    const int chainB[4] = {0, 4, 1, 5};   // w=3,3,5,5
    const int chain = (slot < 16) ? chainA[p] : chainB[p];
    const int pt = sub * 16 + (slot & 15);
    const int dir = chain >> 2, wi = chain & 3;
    const int w = 3 + 2 * wi, half = wi + 1;
    const int tid = threadIdx.x;
    const int lane = tid & 63, wv = tid >> 6;   // wv 0..11 = unit slice
    const int colid = lane & 31, hq = lane >> 5;
    const int uu = wv * 32 + colid;
    const int m0 = pt * 32, b = m0 >> 8, l0 = m0 & 255;

    __shared__ __align__(16) unsigned short Hbuf[2][24 * HSTRIDE];
    float c[16];
#pragma unroll
    for (int r = 0; r < 16; ++r) c[r] = 0.f;

    const unsigned short* projb = proj + (size_t)(b * LL) * PROJ_N + chain * G4 + uu * 4;
    const unsigned short* Wb = Wf + (size_t)((chain * 48 + wv) * 24) * 512 + lane * 8;
    const int ksp = uu >> 4, khp = (uu >> 3) & 1, jp = uu & 7;
    const int hslot = ksp * HSTRIDE + khp * 256 + jp;   // + row*8

    for (int s = 0; s < w; ++s) {
        const int t = dir ? (w - 1 - s) : s;
        const int tmh = t - half;
        unsigned short* cur = Hbuf[s & 1];
        const unsigned short* prev = Hbuf[(s & 1) ^ 1];

        // ---- gate-packed proj prefetch: PLAIN loads (L2-cacheable)
        short4v pj[16];
#pragma unroll
        for (int r = 0; r < 16; ++r) {
            const int row = (r & 3) + 8 * (r >> 2) + 4 * hq;
            int src = l0 + row + tmh;
            src = src < 0 ? 0 : (src > LL - 1 ? LL - 1 : src);
            pj[r] = *(const short4v*)(projb + src * PROJ_N);
        }

        f32x16 acc0 = {}, acc1 = {}, acc2 = {}, acc3 = {};
        if (s > 0) {   // s==0: H is zero, gates = proj only
            const unsigned short* Alds = prev + lane * 8;
#pragma unroll 4
            for (int ks = 0; ks < 24; ++ks) {
                const short8 av  = *(const short8*)(Alds + ks * HSTRIDE);
                const short8 bv0 = *(const short8*)(Wb + (size_t)(0 * 288 + ks) * 512);
                const short8 bv1 = *(const short8*)(Wb + (size_t)(1 * 288 + ks) * 512);
                const short8 bv2 = *(const short8*)(Wb + (size_t)(2 * 288 + ks) * 512);
                const short8 bv3 = *(const short8*)(Wb + (size_t)(3 * 288 + ks) * 512);
                acc0 = __builtin_amdgcn_mfma_f32_32x32x16_bf16(av, bv0, acc0, 0, 0, 0);
                acc1 = __builtin_amdgcn_mfma_f32_32x32x16_bf16(av, bv1, acc1, 0, 0, 0);
                acc2 = __builtin_amdgcn_mfma_f32_32x32x16_bf16(av, bv2, acc2, 0, 0, 0);
                acc3 = __builtin_amdgcn_mfma_f32_32x32x16_bf16(av, bv3, acc3, 0, 0, 0);
            }
        }

#pragma unroll
        for (int r = 0; r < 16; ++r) {
            const int row = (r & 3) + 8 * (r >> 2) + 4 * hq;
            const int src = l0 + row + tmh;
            unsigned short hv;
            if (src >= 0 && src < LL) {
                const float gi = acc0[r] + bf2f((unsigned short)pj[r][0]);
                const float gf = acc1[r] + bf2f((unsigned short)pj[r][1]);
                const float gg = acc2[r] + bf2f((unsigned short)pj[r][2]);
                const float go = acc3[r] + bf2f((unsigned short)pj[r][3]);
                c[r] = fsig(gf) * c[r] + fsig(gi) * ftanh(gg);
                hv = f2bf(fsig(go) * ftanh(c[r]));
            } else {
                hv = (s == 0) ? (unsigned short)0 : prev[hslot + row * 8];
            }
            cur[hslot + row * 8] = hv;
        }
        __syncthreads();   // writes visible before next step's reads
    }

    // ---- final H -> global (unpadded hfrag layout)
    const unsigned short* fin = Hbuf[(w - 1) & 1];
    unsigned short* ho = hfin + (size_t)chain * (NPOS * HH) + (size_t)pt * 12288;
#pragma unroll
    for (int i = tid; i < 1536; i += 768) {
        const int ks = i >> 6, off = i & 63;
        *(int4*)(ho + ks * 512 + off * 8) = *(const int4*)(fin + ks * HSTRIDE + off * 8);
    }
}

// ---------------------------------------------------------------- attention, stage 1: partial scores
__global__ __launch_bounds__(192) void attn_scores_kernel(
        const unsigned short* __restrict__ xfrag,
        const unsigned short* __restrict__ hfin,
        float* __restrict__ scores) {
    const int pt = blockIdx.x >> 3, seg = blockIdx.x & 7;
    const int dir = seg >> 2, q = seg & 3;
    const int tid = threadIdx.x;
    const int lane = tid & 63, wv3 = tid >> 6;
    const int pos = lane & 31;
    __shared__ float scp[3][4][32];

    const unsigned short* xb = xfrag + ((size_t)(pt * 48 + 24 * dir)) * 512 + lane * 8;
    const unsigned short* hb0 = hfin + (size_t)(dir * 4) * (NPOS * HH) + (size_t)pt * 12288 + lane * 8;

    float sc4[4] = {0.f, 0.f, 0.f, 0.f};
#pragma unroll
    for (int k = 0; k < 2; ++k) {
        const int ks = q * 6 + wv3 * 2 + k;
        const short8 xv = *(const short8*)(xb + ks * 512);
        float xf[8];
#pragma unroll
        for (int j = 0; j < 8; ++j) xf[j] = bf2f((unsigned short)xv[j]);
#pragma unroll
        for (int wi = 0; wi < 4; ++wi) {
            const short8 hv = *(const short8*)(hb0 + (size_t)wi * (NPOS * HH) + ks * 512);
#pragma unroll
            for (int j = 0; j < 8; ++j)
                sc4[wi] = fmaf(xf[j], bf2f((unsigned short)hv[j]), sc4[wi]);
        }
    }
#pragma unroll
    for (int wi = 0; wi < 4; ++wi) sc4[wi] += __shfl_down(sc4[wi], 32);
    if (lane < 32) {
#pragma unroll
        for (int wi = 0; wi < 4; ++wi) scp[wv3][wi][pos] = sc4[wi];
    }
    __syncthreads();
    if (tid < 32) {
#pragma unroll
        for (int wi = 0; wi < 4; ++wi) {
            const float v = scp[0][wi][tid] + scp[1][wi][tid] + scp[2][wi][tid];
            scores[(((size_t)pt * 8 + seg) * 4 + wi) * 32 + tid] = v;
        }
    }
}

// ---------------------------------------------------------------- attention, stage 2: softmax + output
__global__ __launch_bounds__(192) void attn_out2_kernel(
        const unsigned short* __restrict__ xfrag,
        const unsigned short* __restrict__ hfin,
        const float* __restrict__ scores,
        const float* __restrict__ lin_w,
        float* __restrict__ out) {
    const int pt = blockIdx.x >> 3, seg = blockIdx.x & 7;
    const int dir = seg >> 2, q = seg & 3;
    const int tid = threadIdx.x;
    const int lane = tid & 63, wv3 = tid >> 6;
    const int pos = lane & 31, kh = lane >> 5;
    const float inv_sqrt_d = 0.03608439182435161f;
    __shared__ float redp[3][32][10];

    float s[4];
#pragma unroll
    for (int wi = 0; wi < 4; ++wi) {
        float v = 0.f;
#pragma unroll
        for (int s2 = 0; s2 < 8; ++s2)
            v += scores[(((size_t)pt * 8 + s2) * 4 + wi) * 32 + pos];
        s[wi] = v * inv_sqrt_d;
    }
    float mx = fmaxf(fmaxf(s[0], s[1]), fmaxf(s[2], s[3]));
    float denom = 0.f;
    float aw[4];
#pragma unroll
    for (int wi = 0; wi < 4; ++wi) { aw[wi] = __expf(s[wi] - mx); denom += aw[wi]; }
    const float rd = __builtin_amdgcn_rcpf(denom);
#pragma unroll
    for (int wi = 0; wi < 4; ++wi) aw[wi] *= rd;

    const unsigned short* xb = xfrag + ((size_t)(pt * 48 + 24 * dir)) * 512 + lane * 8;
    const unsigned short* hb0 = hfin + (size_t)(dir * 4) * (NPOS * HH) + (size_t)pt * 12288 + lane * 8;

    float rp[9];
#pragma unroll
    for (int r = 0; r < 9; ++r) rp[r] = 0.f;
#pragma unroll
    for (int k = 0; k < 2; ++k) {
        const int ks = q * 6 + wv3 * 2 + k;
        const short8 xv = *(const short8*)(xb + ks * 512);
        float ov[8];
#pragma unroll
        for (int j = 0; j < 8; ++j) ov[j] = bf2f((unsigned short)xv[j]);
#pragma unroll
        for (int wi = 0; wi < 4; ++wi) {
            const short8 hv = *(const short8*)(hb0 + (size_t)wi * (NPOS * HH) + ks * 512);
#pragma unroll
            for (int j = 0; j < 8; ++j)
                ov[j] = fmaf(aw[wi], bf2f((unsigned short)hv[j]), ov[j]);
        }
        const int dbase = dir * 384 + ks * 16 + kh * 8;
#pragma unroll
        for (int r = 0; r < 9; ++r) {
            const float4 lw0 = *(const float4*)(lin_w + r * DD + dbase);
            const float4 lw1 = *(const float4*)(lin_w + r * DD + dbase + 4);
            rp[r] += ov[0] * lw0.x + ov[1] * lw0.y + ov[2] * lw0.z + ov[3] * lw0.w
                   + ov[4] * lw1.x + ov[5] * lw1.y + ov[6] * lw1.z + ov[7] * lw1.w;
        }
    }
#pragma unroll
    for (int r = 0; r < 9; ++r) rp[r] += __shfl_down(rp[r], 32);
    if (lane < 32) {
#pragma unroll
        for (int r = 0; r < 9; ++r) redp[wv3][pos][r] = rp[r];
    }
    __syncthreads();
    if (tid < 96) {
#pragma unroll
        for (int e = 0; e < 3; ++e) {
            const int flat = tid * 3 + e;
            const int p2 = flat / 9, r = flat % 9;
            const float sum = redp[0][p2][r] + redp[1][p2][r] + redp[2][p2][r];
            atomicAdd(&out[(size_t)(pt * 32 + p2) * NLIN + r], sum);
        }
    }
}

// ---------------------------------------------------------------- launch
extern "C" void kernel_launch(void* const* d_in, const int* in_sizes, int n_in,
                              void* d_out, int out_size, void* d_ws, size_t ws_size,
                              hipStream_t stream) {
    (void)in_sizes; (void)n_in; (void)out_size; (void)ws_size;
    const float* seq   = (const float*)d_in[0];
    const int*   valid = (const int*)d_in[1];
    const float* wih_f = (const float*)d_in[2];
    const float* whh_f = (const float*)d_in[3];
    const float* bih_f = (const float*)d_in[4];
    const float* bhh_f = (const float*)d_in[5];
    const float* wih_b = (const float*)d_in[6];
    const float* whh_b = (const float*)d_in[7];
    const float* bih_b = (const float*)d_in[8];
    const float* bhh_b = (const float*)d_in[9];
    const float* lin_w = (const float*)d_in[10];
    const float* lin_b = (const float*)d_in[11];
    float* out = (float*)d_out;

    // workspace layout (~61.5 MB)
    unsigned short* xfrag = (unsigned short*)d_ws;                 // 786432 bf16
    unsigned short* proj  = xfrag + (size_t)NPOS * DD;             // 12582912 bf16
    unsigned short* wfhh  = proj + (size_t)NPOS * PROJ_N;          // 4718592 bf16
    unsigned short* wfih  = wfhh + (size_t)4718592;                // 9437184 bf16
    unsigned short* hfin  = wfih + (size_t)9437184;                // 3145728 bf16
    float* scores = (float*)(hfin + (size_t)3145728);              // 128 KB

    prep_kernel<<<897, 256, 0, stream>>>(seq, valid, xfrag,
                                         wih_f, wih_b, wfih,
                                         whh_f, whh_b, wfhh,
                                         lin_b, out);
    proj_mfma<<<768, 256, 0, stream>>>(xfrag, wfih, bih_f, bhh_f, bih_b, bhh_b, proj);
    lstm_fused<<<256, 768, 0, stream>>>(wfhh, proj, hfin);
    attn_scores_kernel<<<256, 192, 0, stream>>>(xfrag, hfin, scores);
    attn_out2_kernel<<<256, 192, 0, stream>>>(xfrag, hfin, scores, lin_w, out);
}

// Round 10
// 267.923 us; speedup vs baseline: 1.1242x; 1.0350x over previous
//
#include <hip/hip_runtime.h>
#include <math.h>

#define LL 256
#define DD 768
#define HH 384
#define G4 1536
#define NWIN 4
#define NLIN 9
#define NPOS 1024        // B*L
#define PROJ_N 12288     // 8 chains * 1536
#define HSTRIDE 520      // padded LDS ks-stride (shorts): bank-spreads H writes
#define PSLOTS 33        // proj LDS ring slots (33 > 32-row live window)

typedef __attribute__((ext_vector_type(8))) short short8;
typedef __attribute__((ext_vector_type(4))) short short4v;
typedef __attribute__((ext_vector_type(16))) float f32x16;

static __device__ __forceinline__ float bf2f(unsigned short u) {
    union { unsigned int i; float f; } v; v.i = ((unsigned int)u) << 16; return v.f;
}
static __device__ __forceinline__ unsigned short f2bf(float f) {
    unsigned int u = __float_as_uint(f);
    u += 0x7fff + ((u >> 16) & 1);   // round-to-nearest-even
    return (unsigned short)(u >> 16);
}
static __device__ __forceinline__ float fsig(float x) {
    return __builtin_amdgcn_rcpf(1.f + __expf(-x));
}
static __device__ __forceinline__ float ftanh(float x) {
    return 1.f - 2.f * __builtin_amdgcn_rcpf(1.f + __expf(2.f * x));
}

// ---------------------------------------------------------------- prep: scatter(+zero), weight casts, out-init
__global__ __launch_bounds__(256) void prep_kernel(
        const float* __restrict__ seq, const int* __restrict__ valid,
        unsigned short* __restrict__ xfrag,
        const float* __restrict__ wihF, const float* __restrict__ wihB,
        unsigned short* __restrict__ wfih,
        const float* __restrict__ whhF, const float* __restrict__ whhB,
        unsigned short* __restrict__ wfhh,
        const float* __restrict__ lin_b, float* __restrict__ out) {
    const int tid = threadIdx.x;
    if (blockIdx.x < 128) {
        // ---------------- scatter + tail-zero (ballot-scan)
        const int b = blockIdx.x >> 5;
        const int chunk = blockIdx.x & 31;
        __shared__ int dest[LL];
        __shared__ int wsum[4];
        __shared__ int nvalid;
        const int v = valid[b * LL + tid];
        const unsigned long long m = __ballot(v != 0);
        const int lane = tid & 63, wvi = tid >> 6;
        const int pre = __popcll(m & (((unsigned long long)1 << lane) - 1));
        if (lane == 63) wsum[wvi] = pre + (v ? 1 : 0);
        __syncthreads();
        int base = 0;
#pragma unroll
        for (int k = 0; k < 4; ++k) if (k < wvi) base += wsum[k];
        dest[tid] = v ? (base + pre) : -1;
        if (tid == 0) nvalid = wsum[0] + wsum[1] + wsum[2] + wsum[3];
        __syncthreads();
        const int nv = nvalid;
        for (int l = chunk * 8; l < chunk * 8 + 8; ++l) {
            const int d = dest[l];
            if (d >= 0) {
                const float* src = seq + (size_t)(b * LL + l) * DD;
                const int pos = b * LL + d;
                const int pt = pos >> 5, pl = pos & 31;
                for (int j = tid; j < DD / 8; j += 256) {
                    const float4 v0 = ((const float4*)src)[2 * j];
                    const float4 v1 = ((const float4*)src)[2 * j + 1];
                    short8 pv;
                    pv[0] = (short)f2bf(v0.x); pv[1] = (short)f2bf(v0.y);
                    pv[2] = (short)f2bf(v0.z); pv[3] = (short)f2bf(v0.w);
                    pv[4] = (short)f2bf(v1.x); pv[5] = (short)f2bf(v1.y);
                    pv[6] = (short)f2bf(v1.z); pv[7] = (short)f2bf(v1.w);
                    *(short8*)(xfrag + ((size_t)(pt * 48 + (j >> 1)) * 512 + (pl + 32 * (j & 1)) * 8)) = pv;
                }
            }
            if (l >= nv) {   // dest slot l never written: zero its frag row
                const int pos = b * LL + l;
                const int pt = pos >> 5, pl = pos & 31;
                const short8 zv = {};
                for (int j = tid; j < DD / 8; j += 256)
                    *(short8*)(xfrag + ((size_t)(pt * 48 + (j >> 1)) * 512 + (pl + 32 * (j & 1)) * 8)) = zv;
            }
        }
    } else if (blockIdx.x < 896) {
        // ---------------- cast weights -> B-fragment layout
        __shared__ unsigned short lds[32 * 768];
        const int cb = blockIdx.x - 128;
        const int isIH = cb < 384;
        const int vblk = isIH ? cb : (cb - 384);
        const int K = isIH ? DD : HH;
        const float* srcF = isIH ? wihF : whhF;
        const float* srcB = isIH ? wihB : whhB;
        unsigned short* dst = isIH ? wfih : wfhh;
        const int vrow0 = vblk * 32;
        const int chain = vrow0 / G4;
        const int dir = chain >> 2, wi = chain & 3;
        const float* src = (dir ? srcB : srcF) + (size_t)(wi * G4 + (vrow0 % G4)) * K;
        const int total = 32 * K;
        for (int i = tid * 4; i < total; i += 1024) {
            const float4 v = *(const float4*)(src + i);
            lds[i + 0] = f2bf(v.x); lds[i + 1] = f2bf(v.y);
            lds[i + 2] = f2bf(v.z); lds[i + 3] = f2bf(v.w);
        }
        __syncthreads();
        const int nks = K >> 4;
        for (int slot = tid; slot < nks * 64; slot += 256) {
            const int ks = slot >> 6;
            const int lane = slot & 63;
            const int row = lane & 31;
            const int kb = ks * 16 + (lane >> 5) * 8;
            const short8 v = *(const short8*)&lds[row * K + kb];
            *(short8*)(dst + ((size_t)vblk * nks + ks) * 512 + lane * 8) = v;
        }
    } else {
        // ---------------- seed out with lin_b (attn_out2 atomicAdds partials)
        for (int i = tid; i < NPOS * NLIN; i += 256)
            out[i] = lin_b[i % NLIN];
    }
}

// ---------------------------------------------------------------- proj GEMM (MFMA)
__global__ __launch_bounds__(256) void proj_mfma(
        const unsigned short* __restrict__ xf,
        const unsigned short* __restrict__ wf,
        const float* __restrict__ bihf, const float* __restrict__ bhhf,
        const float* __restrict__ bihb, const float* __restrict__ bhhb,
        unsigned short* __restrict__ proj) {
    __shared__ __align__(16) unsigned short st[4 * 4096];   // 32 KB
    const int wv = threadIdx.x >> 6;        // gate
    const int lane = threadIdx.x & 63;
    const int colid = lane & 31, hq = lane >> 5;
    const int chain = blockIdx.x & 7;       // XCD id
    const int r8 = blockIdx.x >> 3;         // 0..95
    const int us = r8 % 12;
    const int mtg = r8 / 12;                // 0..7
    const int dir = chain >> 2, wi = chain & 3;

    const unsigned short* bP = wf + (size_t)((chain * 48 + wv * 12 + us) * 48) * 512 + lane * 8;
    const unsigned short* aP = xf + (size_t)(mtg * 4 * 48) * 512 + lane * 8;

    f32x16 acc[4] = {};
#pragma unroll 4
    for (int ks = 0; ks < 48; ++ks) {
        const short8 bv = *(const short8*)(bP + ks * 512);
        const short8 a0 = *(const short8*)(aP + (0 * 48 + ks) * 512);
        const short8 a1 = *(const short8*)(aP + (1 * 48 + ks) * 512);
        const short8 a2 = *(const short8*)(aP + (2 * 48 + ks) * 512);
        const short8 a3 = *(const short8*)(aP + (3 * 48 + ks) * 512);
        acc[0] = __builtin_amdgcn_mfma_f32_32x32x16_bf16(a0, bv, acc[0], 0, 0, 0);
        acc[1] = __builtin_amdgcn_mfma_f32_32x32x16_bf16(a1, bv, acc[1], 0, 0, 0);
        acc[2] = __builtin_amdgcn_mfma_f32_32x32x16_bf16(a2, bv, acc[2], 0, 0, 0);
        acc[3] = __builtin_amdgcn_mfma_f32_32x32x16_bf16(a3, bv, acc[3], 0, 0, 0);
    }
    const int br = wv * HH + us * 32 + colid;
    const float bv = (dir ? bihb : bihf)[wi * G4 + br] + (dir ? bhhb : bhhf)[wi * G4 + br];
#pragma unroll
    for (int i = 0; i < 4; ++i) {
#pragma unroll
        for (int r = 0; r < 16; ++r) {
            const int row = (r & 3) + 8 * (r >> 2) + 4 * hq;
            st[i * 4096 + (row * 32 + colid) * 4 + wv] = f2bf(acc[i][r] + bv);
        }
    }
    __syncthreads();
#pragma unroll
    for (int j = 0; j < 8; ++j) {
        const int idx = j * 256 + threadIdx.x;
        const int i = idx >> 9, rem = idx & 511;
        const int pl = rem >> 4, q = rem & 15;
        const int pos = (mtg * 4 + i) * 32 + pl;
        *(int4*)(proj + (size_t)pos * PROJ_N + chain * G4 + us * 128 + q * 8) =
            ((const int4*)st)[idx];
    }
}

// ---------------------------------------------------------------- fused LSTM recurrence (r0 structure + proj LDS ring)
// FALSIFIED ledger, do not retry: XCD remap (r1), reg W-pipeline (r2),
// M=64 (r4/r5, 84-VGPR compiler pin), launch_bounds (r5), K-stagger (r6),
// two-pass gates (r8). CONFIRMED (r9): proj-load latency is on the
// critical path (dropping NT: 156->140 us) but cached proj evicts W
// (FETCH 57->71 MB).
// THIS ROUND: proj window -> LDS RING. The 32-row clamped window shifts
// by 1/step, so each step needs ONE new 3072-B row = one 4-B load/thread,
// issued at step top (latency hidden under MFMA), committed to LDS before
// the barrier. slot = src % 33: live window spans <=33 contiguous srcs ->
// no collision; clamp duplicates write identical bytes (benign). Effects:
// proj global traffic /w (W stays L2-resident -> FETCH should DROP), proj
// latency chain leaves the critical path, pj[16] (32 VGPRs) freed during
// MFMA. LDS 49.9+101.4 = 151.3 KB (<=160); grid is 1 block/CU anyway.
// Spill sentinel: WRITE must stay ~8.4 MB.
__global__ __launch_bounds__(768, 1) void lstm_fused(
        const unsigned short* __restrict__ Wf,
        const unsigned short* __restrict__ proj,
        unsigned short* __restrict__ hfin) {
    const int p = blockIdx.x & 3, sub = (blockIdx.x >> 2) & 1;
    const int slot = blockIdx.x >> 3;
    const int chainA[4] = {3, 7, 2, 6};   // w=9,9,7,7
    const int chainB[4] = {0, 4, 1, 5};   // w=3,3,5,5
    const int chain = (slot < 16) ? chainA[p] : chainB[p];
    const int pt = sub * 16 + (slot & 15);
    const int dir = chain >> 2, wi = chain & 3;
    const int w = 3 + 2 * wi, half = wi + 1;
    const int tid = threadIdx.x;
    const int lane = tid & 63, wv = tid >> 6;   // wv 0..11 = unit slice
    const int colid = lane & 31, hq = lane >> 5;
    const int uu = wv * 32 + colid;
    const int m0 = pt * 32, b = m0 >> 8, l0 = m0 & 255;

    __shared__ __align__(16) unsigned short Hbuf[2][24 * HSTRIDE];   // 49.9 KB
    __shared__ __align__(16) unsigned short Pring[PSLOTS][1536];     // 101.4 KB
    float c[16];
#pragma unroll
    for (int r = 0; r < 16; ++r) c[r] = 0.f;

    // proj rows for this (batch, chain), viewed as uints (768 per row)
    const unsigned int* projU = (const unsigned int*)(proj
        + (size_t)(b * LL) * PROJ_N + chain * G4);
    const unsigned short* Wb = Wf + (size_t)((chain * 48 + wv) * 24) * 512 + lane * 8;
    const int ksp = uu >> 4, khp = (uu >> 3) & 1, jp = uu & 7;
    const int hslot = ksp * HSTRIDE + khp * 256 + jp;   // + row*8

    // ---- preload step-0's 32-row window into the ring
    const int t0 = dir ? (w - 1) : 0;
    for (int i = 0; i < 32; ++i) {
        int src = l0 + i + t0 - half;
        src = src < 0 ? 0 : (src > LL - 1 ? LL - 1 : src);
        ((unsigned int*)&Pring[src % PSLOTS][0])[tid] =
            projU[(size_t)src * (PROJ_N / 2) + tid];
    }
    __syncthreads();

    for (int s = 0; s < w; ++s) {
        const int t = dir ? (w - 1 - s) : s;
        const int tmh = t - half;
        unsigned short* cur = Hbuf[s & 1];
        const unsigned short* prev = Hbuf[(s & 1) ^ 1];

        // ---- issue next step's single new row early (hidden under MFMA)
        int nsrc = -1;
        unsigned int pref = 0;
        if (s + 1 < w) {
            const int tn = dir ? (w - 2 - s) : (s + 1);
            nsrc = dir ? (l0 + tn - half) : (l0 + 31 + tn - half);
            nsrc = nsrc < 0 ? 0 : (nsrc > LL - 1 ? LL - 1 : nsrc);
            pref = projU[(size_t)nsrc * (PROJ_N / 2) + tid];
        }

        f32x16 acc0 = {}, acc1 = {}, acc2 = {}, acc3 = {};
        if (s > 0) {   // s==0: H is zero, gates = proj only
            const unsigned short* Alds = prev + lane * 8;
#pragma unroll 4
            for (int ks = 0; ks < 24; ++ks) {
                const short8 av  = *(const short8*)(Alds + ks * HSTRIDE);
                const short8 bv0 = *(const short8*)(Wb + (size_t)(0 * 288 + ks) * 512);
                const short8 bv1 = *(const short8*)(Wb + (size_t)(1 * 288 + ks) * 512);
                const short8 bv2 = *(const short8*)(Wb + (size_t)(2 * 288 + ks) * 512);
                const short8 bv3 = *(const short8*)(Wb + (size_t)(3 * 288 + ks) * 512);
                acc0 = __builtin_amdgcn_mfma_f32_32x32x16_bf16(av, bv0, acc0, 0, 0, 0);
                acc1 = __builtin_amdgcn_mfma_f32_32x32x16_bf16(av, bv1, acc1, 0, 0, 0);
                acc2 = __builtin_amdgcn_mfma_f32_32x32x16_bf16(av, bv2, acc2, 0, 0, 0);
                acc3 = __builtin_amdgcn_mfma_f32_32x32x16_bf16(av, bv3, acc3, 0, 0, 0);
            }
        }

#pragma unroll
        for (int r = 0; r < 16; ++r) {
            const int row = (r & 3) + 8 * (r >> 2) + 4 * hq;
            const int src = l0 + row + tmh;
            const int cs = src < 0 ? 0 : (src > LL - 1 ? LL - 1 : src);
            unsigned short hv;
            if (src >= 0 && src < LL) {
                const short4v pj = *(const short4v*)&Pring[cs % PSLOTS][uu * 4];
                const float gi = acc0[r] + bf2f((unsigned short)pj[0]);
                const float gf = acc1[r] + bf2f((unsigned short)pj[1]);
                const float gg = acc2[r] + bf2f((unsigned short)pj[2]);
                const float go = acc3[r] + bf2f((unsigned short)pj[3]);
                c[r] = fsig(gf) * c[r] + fsig(gi) * ftanh(gg);
                hv = f2bf(fsig(go) * ftanh(c[r]));
            } else {
                hv = (s == 0) ? (unsigned short)0 : prev[hslot + row * 8];
            }
            cur[hslot + row * 8] = hv;
        }

        // ---- commit prefetched row (identical bytes if clamp-duplicate)
        if (nsrc >= 0)
            ((unsigned int*)&Pring[nsrc % PSLOTS][0])[tid] = pref;
        __syncthreads();   // Hbuf + Pring writes visible for next step
    }

    // ---- final H -> global (unpadded hfrag layout)
    const unsigned short* fin = Hbuf[(w - 1) & 1];
    unsigned short* ho = hfin + (size_t)chain * (NPOS * HH) + (size_t)pt * 12288;
#pragma unroll
    for (int i = tid; i < 1536; i += 768) {
        const int ks = i >> 6, off = i & 63;
        *(int4*)(ho + ks * 512 + off * 8) = *(const int4*)(fin + ks * HSTRIDE + off * 8);
    }
}

// ---------------------------------------------------------------- attention, stage 1: partial scores
__global__ __launch_bounds__(192) void attn_scores_kernel(
        const unsigned short* __restrict__ xfrag,
        const unsigned short* __restrict__ hfin,
        float* __restrict__ scores) {
    const int pt = blockIdx.x >> 3, seg = blockIdx.x & 7;
    const int dir = seg >> 2, q = seg & 3;
    const int tid = threadIdx.x;
    const int lane = tid & 63, wv3 = tid >> 6;
    const int pos = lane & 31;
    __shared__ float scp[3][4][32];

    const unsigned short* xb = xfrag + ((size_t)(pt * 48 + 24 * dir)) * 512 + lane * 8;
    const unsigned short* hb0 = hfin + (size_t)(dir * 4) * (NPOS * HH) + (size_t)pt * 12288 + lane * 8;

    float sc4[4] = {0.f, 0.f, 0.f, 0.f};
#pragma unroll
    for (int k = 0; k < 2; ++k) {
        const int ks = q * 6 + wv3 * 2 + k;
        const short8 xv = *(const short8*)(xb + ks * 512);
        float xf[8];
#pragma unroll
        for (int j = 0; j < 8; ++j) xf[j] = bf2f((unsigned short)xv[j]);
#pragma unroll
        for (int wi = 0; wi < 4; ++wi) {
            const short8 hv = *(const short8*)(hb0 + (size_t)wi * (NPOS * HH) + ks * 512);
#pragma unroll
            for (int j = 0; j < 8; ++j)
                sc4[wi] = fmaf(xf[j], bf2f((unsigned short)hv[j]), sc4[wi]);
        }
    }
#pragma unroll
    for (int wi = 0; wi < 4; ++wi) sc4[wi] += __shfl_down(sc4[wi], 32);
    if (lane < 32) {
#pragma unroll
        for (int wi = 0; wi < 4; ++wi) scp[wv3][wi][pos] = sc4[wi];
    }
    __syncthreads();
    if (tid < 32) {
#pragma unroll
        for (int wi = 0; wi < 4; ++wi) {
            const float v = scp[0][wi][tid] + scp[1][wi][tid] + scp[2][wi][tid];
            scores[(((size_t)pt * 8 + seg) * 4 + wi) * 32 + tid] = v;
        }
    }
}

// ---------------------------------------------------------------- attention, stage 2: softmax + output
__global__ __launch_bounds__(192) void attn_out2_kernel(
        const unsigned short* __restrict__ xfrag,
        const unsigned short* __restrict__ hfin,
        const float* __restrict__ scores,
        const float* __restrict__ lin_w,
        float* __restrict__ out) {
    const int pt = blockIdx.x >> 3, seg = blockIdx.x & 7;
    const int dir = seg >> 2, q = seg & 3;
    const int tid = threadIdx.x;
    const int lane = tid & 63, wv3 = tid >> 6;
    const int pos = lane & 31, kh = lane >> 5;
    const float inv_sqrt_d = 0.03608439182435161f;
    __shared__ float redp[3][32][10];

    float s[4];
#pragma unroll
    for (int wi = 0; wi < 4; ++wi) {
        float v = 0.f;
#pragma unroll
        for (int s2 = 0; s2 < 8; ++s2)
            v += scores[(((size_t)pt * 8 + s2) * 4 + wi) * 32 + pos];
        s[wi] = v * inv_sqrt_d;
    }
    float mx = fmaxf(fmaxf(s[0], s[1]), fmaxf(s[2], s[3]));
    float denom = 0.f;
    float aw[4];
#pragma unroll
    for (int wi = 0; wi < 4; ++wi) { aw[wi] = __expf(s[wi] - mx); denom += aw[wi]; }
    const float rd = __builtin_amdgcn_rcpf(denom);
#pragma unroll
    for (int wi = 0; wi < 4; ++wi) aw[wi] *= rd;

    const unsigned short* xb = xfrag + ((size_t)(pt * 48 + 24 * dir)) * 512 + lane * 8;
    const unsigned short* hb0 = hfin + (size_t)(dir * 4) * (NPOS * HH) + (size_t)pt * 12288 + lane * 8;

    float rp[9];
#pragma unroll
    for (int r = 0; r < 9; ++r) rp[r] = 0.f;
#pragma unroll
    for (int k = 0; k < 2; ++k) {
        const int ks = q * 6 + wv3 * 2 + k;
        const short8 xv = *(const short8*)(xb + ks * 512);
        float ov[8];
#pragma unroll
        for (int j = 0; j < 8; ++j) ov[j] = bf2f((unsigned short)xv[j]);
#pragma unroll
        for (int wi = 0; wi < 4; ++wi) {
            const short8 hv = *(const short8*)(hb0 + (size_t)wi * (NPOS * HH) + ks * 512);
#pragma unroll
            for (int j = 0; j < 8; ++j)
                ov[j] = fmaf(aw[wi], bf2f((unsigned short)hv[j]), ov[j]);
        }
        const int dbase = dir * 384 + ks * 16 + kh * 8;
#pragma unroll
        for (int r = 0; r < 9; ++r) {
            const float4 lw0 = *(const float4*)(lin_w + r * DD + dbase);
            const float4 lw1 = *(const float4*)(lin_w + r * DD + dbase + 4);
            rp[r] += ov[0] * lw0.x + ov[1] * lw0.y + ov[2] * lw0.z + ov[3] * lw0.w
                   + ov[4] * lw1.x + ov[5] * lw1.y + ov[6] * lw1.z + ov[7] * lw1.w;
        }
    }
#pragma unroll
    for (int r = 0; r < 9; ++r) rp[r] += __shfl_down(rp[r], 32);
    if (lane < 32) {
#pragma unroll
        for (int r = 0; r < 9; ++r) redp[wv3][pos][r] = rp[r];
    }
    __syncthreads();
    if (tid < 96) {
#pragma unroll
        for (int e = 0; e < 3; ++e) {
            const int flat = tid * 3 + e;
            const int p2 = flat / 9, r = flat % 9;
            const float sum = redp[0][p2][r] + redp[1][p2][r] + redp[2][p2][r];
            atomicAdd(&out[(size_t)(pt * 32 + p2) * NLIN + r], sum);
        }
    }
}

// ---------------------------------------------------------------- launch
extern "C" void kernel_launch(void* const* d_in, const int* in_sizes, int n_in,
                              void* d_out, int out_size, void* d_ws, size_t ws_size,
                              hipStream_t stream) {
    (void)in_sizes; (void)n_in; (void)out_size; (void)ws_size;
    const float* seq   = (const float*)d_in[0];
    const int*   valid = (const int*)d_in[1];
    const float* wih_f = (const float*)d_in[2];
    const float* whh_f = (const float*)d_in[3];
    const float* bih_f = (const float*)d_in[4];
    const float* bhh_f = (const float*)d_in[5];
    const float* wih_b = (const float*)d_in[6];
    const float* whh_b = (const float*)d_in[7];
    const float* bih_b = (const float*)d_in[8];
    const float* bhh_b = (const float*)d_in[9];
    const float* lin_w = (const float*)d_in[10];
    const float* lin_b = (const float*)d_in[11];
    float* out = (float*)d_out;

    // workspace layout (~61.5 MB)
    unsigned short* xfrag = (unsigned short*)d_ws;                 // 786432 bf16
    unsigned short* proj  = xfrag + (size_t)NPOS * DD;             // 12582912 bf16
    unsigned short* wfhh  = proj + (size_t)NPOS * PROJ_N;          // 4718592 bf16
    unsigned short* wfih  = wfhh + (size_t)4718592;                // 9437184 bf16
    unsigned short* hfin  = wfih + (size_t)9437184;                // 3145728 bf16
    float* scores = (float*)(hfin + (size_t)3145728);              // 128 KB

    prep_kernel<<<897, 256, 0, stream>>>(seq, valid, xfrag,
                                         wih_f, wih_b, wfih,
                                         whh_f, whh_b, wfhh,
                                         lin_b, out);
    proj_mfma<<<768, 256, 0, stream>>>(xfrag, wfih, bih_f, bhh_f, bih_b, bhh_b, proj);
    lstm_fused<<<256, 768, 0, stream>>>(wfhh, proj, hfin);
    attn_scores_kernel<<<256, 192, 0, stream>>>(xfrag, hfin, scores);
    attn_out2_kernel<<<256, 192, 0, stream>>>(xfrag, hfin, scores, lin_w, out);
}